// Round 17
// baseline (128.489 us; speedup 1.0000x reference)
//
#include <hip/hip_runtime.h>

// Stand-alone self-attention block, fully fused.
// x:(8,64,128,128) f32 -> out same shape. G=8, Cg=8, 3x3 window, pad 1.
//
// R17 = R11 (best, 27.9us: 32x32 tile x 2-ch chunk, 4 px/thread, 4096
// blocks, SGPR weights, stride-38 interleaved float2 kv LDS, b128 window
// reads, scalar streaming no-max exp2 softmax, launch_bounds(256,5))
// + two latency micro-levers:
//  - x interior+halo VMEM issued BEFORE weight sloads (HBM latency
//    overlaps the 66-s_load staging sequence)
//  - s_setprio(1) around the attention phase (T5: CU hosts phase-diverse
//    blocks -> attn waves get issue priority over conv VMEM-waiters)

typedef float v2f __attribute__((ext_vector_type(2)));
typedef float v4f __attribute__((ext_vector_type(4)));

#define HH 128
#define WW 128
#define HW (HH * WW)
#define PT 34          // padded tile extent (32 + halo)
#define PTS 38         // row stride in float2 (34 + 4 pad)
#define LOG2E 1.44269504088896f

__device__ __forceinline__ float sload(float v) {
    // force block-uniform value into an SGPR
    return __uint_as_float(__builtin_amdgcn_readfirstlane(__float_as_uint(v)));
}

__global__ __launch_bounds__(256, 5) void sab_fused(
    const float* __restrict__ x,
    const float* __restrict__ Wq,
    const float* __restrict__ Wk,
    const float* __restrict__ Wv,
    const float* __restrict__ h_emb,
    const float* __restrict__ w_emb,
    float* __restrict__ out)
{
    __shared__ v2f kv[2][PT][PTS];      // [cc][row][col] {k,v}  (20.7 KB)

    const int bid0 = blockIdx.x;
    const int work = (bid0 & 7) * 512 + (bid0 >> 3);   // bijective XCD swizzle
    const int c0   = (work & 3) << 1;          // channel chunk {0,2,4,6}
    const int tile = (work >> 2) & 15;         // 4x4 tiles of 32x32
    const int bg   = work >> 6;                // b*8 + g
    const int g    = bg & 7;
    const int h0   = (tile >> 2) << 5;
    const int w0   = (tile & 3) << 5;
    const int tid  = threadIdx.x;
    const int ty   = tid >> 3;                 // 0..31
    const int x0   = (tid & 7) << 2;           // 0,4,..,28

    const float* xb = x + (size_t)bg * 8 * HW;
    const int ibase = (h0 + ty) * WW + (w0 + x0);

    // ---- issue ALL x VMEM first (latency overlaps weight staging) ----
    v4f xi[8];
    #pragma unroll
    for (int i = 0; i < 8; i++)
        xi[i] = *reinterpret_cast<const v4f*>(xb + i * HW + ibase);

    int hpy = 0, hpx = 0;
    const bool is_halo = tid < 132;
    if (is_halo) {
        if (tid < 34)       { hpy = 0;        hpx = tid; }
        else if (tid < 68)  { hpy = 33;       hpx = tid - 34; }
        else if (tid < 100) { hpy = tid - 67; hpx = 0; }     // rows 1..32
        else                { hpy = tid - 99; hpx = 33; }
    }
    const int hgh = h0 + hpy - 1, hgw = w0 + hpx - 1;
    const bool hok = is_halo & (hgh >= 0) & (hgh < HH) & (hgw >= 0) & (hgw < WW);
    const int hbase = hgh * WW + hgw;
    float hx[8];
    #pragma unroll
    for (int i = 0; i < 8; i++)
        hx[i] = hok ? xb[i * HW + hbase] : 0.0f;

    // ---- weights + emb -> SGPRs (readfirstlane-forced) ----
    float wk[2][8], wv[2][8], wq[2][8], eb[2][9];
    #pragma unroll
    for (int cc = 0; cc < 2; cc++) {
        const int c = c0 + cc;
        #pragma unroll
        for (int i = 0; i < 8; i++) {
            wk[cc][i] = sload(Wk[g * 64 + c * 8 + i]);
            wv[cc][i] = sload(Wv[g * 64 + c * 8 + i]);
            wq[cc][i] = sload(Wq[g * 64 + c * 8 + i]);
        }
        #pragma unroll
        for (int p = 0; p < 9; p++) {
            // channels 0-3: h_emb (ki = p/3); 4-7: w_emb (kj = p%3)
            eb[cc][p] = sload((c < 4) ? h_emb[(g * 4 + c) * 3 + p / 3]
                                      : w_emb[(g * 4 + c - 4) * 3 + p % 3]);
        }
    }

    // ---- conv (packed): k,v -> LDS, q -> regs ----
    v4f kk0 = 0.f, vv0 = 0.f, qq0 = 0.f, kk1 = 0.f, vv1 = 0.f, qq1 = 0.f;
    #pragma unroll
    for (int i = 0; i < 8; i++) {
        const v4f xv = xi[i];
        kk0 += wk[0][i] * xv;  vv0 += wv[0][i] * xv;  qq0 += wq[0][i] * xv;
        kk1 += wk[1][i] * xv;  vv1 += wv[1][i] * xv;  qq1 += wq[1][i] * xv;
    }
    #pragma unroll
    for (int px = 0; px < 4; px++) {
        kv[0][ty + 1][x0 + 1 + px] = (v2f){kk0[px], vv0[px]};
        kv[1][ty + 1][x0 + 1 + px] = (v2f){kk1[px], vv1[px]};
    }
    float q[2][4];
    #pragma unroll
    for (int px = 0; px < 4; px++) {
        q[0][px] = qq0[px] * LOG2E;
        q[1][px] = qq1[px] * LOG2E;
    }

    // ---- halo conv (x already in hx regs) ----
    if (is_halo) {
        float hk0 = 0.f, hv0 = 0.f, hk1 = 0.f, hv1 = 0.f;
        #pragma unroll
        for (int i = 0; i < 8; i++) {
            hk0 = fmaf(wk[0][i], hx[i], hk0);
            hv0 = fmaf(wv[0][i], hx[i], hv0);
            hk1 = fmaf(wk[1][i], hx[i], hk1);
            hv1 = fmaf(wv[1][i], hx[i], hv1);
        }
        kv[0][hpy][hpx] = (v2f){hk0, hv0};
        kv[1][hpy][hpx] = (v2f){hk1, hv1};
    }
    __syncthreads();

    // ---- attention: scalar streaming softmax, priority-boosted ----
    __builtin_amdgcn_s_setprio(1);
    float s[2][4] = {{0.f,0.f,0.f,0.f},{0.f,0.f,0.f,0.f}};
    float o[2][4] = {{0.f,0.f,0.f,0.f},{0.f,0.f,0.f,0.f}};
    #pragma unroll
    for (int dh = 0; dh < 3; dh++) {
        #pragma unroll
        for (int cc = 0; cc < 2; cc++) {
            const v2f* row = &kv[cc][ty + dh][x0];
            const v4f a  = *reinterpret_cast<const v4f*>(row);      // k0 v0 k1 v1
            const v4f bq = *reinterpret_cast<const v4f*>(row + 2);  // k2 v2 k3 v3
            const v4f cq = *reinterpret_cast<const v4f*>(row + 4);  // k4 v4 k5 v5
            const float kw[6] = {a.x, a.z, bq.x, bq.z, cq.x, cq.z};
            const float vw[6] = {a.y, a.w, bq.y, bq.w, cq.y, cq.w};
            #pragma unroll
            for (int px = 0; px < 4; px++) {
                const float ql = q[cc][px];
                #pragma unroll
                for (int dw = 0; dw < 3; dw++) {
                    const float e = __builtin_amdgcn_exp2f(
                        ql * (kw[px + dw] + eb[cc][dh * 3 + dw]));
                    s[cc][px] += e;
                    o[cc][px] = fmaf(e, vw[px + dw], o[cc][px]);
                }
            }
        }
    }
    __builtin_amdgcn_s_setprio(0);

    // ---- normalize + store (dwordx4 per channel) ----
    v4f r0, r1;
    #pragma unroll
    for (int px = 0; px < 4; px++) {
        r0[px] = o[0][px] * __builtin_amdgcn_rcpf(s[0][px]);
        r1[px] = o[1][px] * __builtin_amdgcn_rcpf(s[1][px]);
    }
    *reinterpret_cast<v4f*>(out + (size_t)(bg * 8 + c0 + 0) * HW + ibase) = r0;
    *reinterpret_cast<v4f*>(out + (size_t)(bg * 8 + c0 + 1) * HW + ibase) = r1;
}

extern "C" void kernel_launch(void* const* d_in, const int* in_sizes, int n_in,
                              void* d_out, int out_size, void* d_ws, size_t ws_size,
                              hipStream_t stream) {
    const float* x    = (const float*)d_in[0];
    const float* Wq   = (const float*)d_in[1];
    const float* Wk   = (const float*)d_in[2];
    const float* Wv   = (const float*)d_in[3];
    const float* h_e  = (const float*)d_in[4];
    const float* w_e  = (const float*)d_in[5];
    float* out = (float*)d_out;

    dim3 grid(8 * 8 * 16 * 4);   // (b,g) x 4x4 tiles x 4 channel-chunks
    dim3 block(256);
    sab_fused<<<grid, block, 0, stream>>>(x, Wq, Wk, Wv, h_e, w_e, out);
}

// Round 18
// 28.208 us; speedup vs baseline: 4.5550x; 4.5550x over previous
//
#include <hip/hip_runtime.h>

// Stand-alone self-attention block, fully fused. FINAL = R11 (best, 27.9us).
// x:(8,64,128,128) f32 -> out same shape. G=8, Cg=8, 3x3 window, pad 1.
//
// Structure: 32x32 tile x 2-ch chunk, 4 px/thread, 4096 blocks, SGPR
// weights (readfirstlane), stride-38 interleaved float2 kv LDS, b128
// window reads, scalar streaming no-max exp2 softmax, launch_bounds(256,5).
//
// Session ledger (why this shape): channel widths {2 best, 4, 8}, tiles
// {16^2, 32^2 best, 32x16, 64x16, 128x8}, occupancy-forcing (4 allocator
// collapses: R6/R9/R13/R17), chunk fusion (R10), double-buffer pipelining
// (R16), pk-f32 VALU halving (~0, R8), full-width coalescing (R14),
// x-load hoisting (R17 collapse) -- all measured <= this kernel.
// Regime: latency-bound plateau, all pipes <65%.

typedef float v2f __attribute__((ext_vector_type(2)));
typedef float v4f __attribute__((ext_vector_type(4)));

#define HH 128
#define WW 128
#define HW (HH * WW)
#define PT 34          // padded tile extent (32 + halo)
#define PTS 38         // row stride in float2 (34 + 4 pad)
#define LOG2E 1.44269504088896f

__device__ __forceinline__ float sload(float v) {
    // force block-uniform value into an SGPR
    return __uint_as_float(__builtin_amdgcn_readfirstlane(__float_as_uint(v)));
}

__global__ __launch_bounds__(256, 5) void sab_fused(
    const float* __restrict__ x,
    const float* __restrict__ Wq,
    const float* __restrict__ Wk,
    const float* __restrict__ Wv,
    const float* __restrict__ h_emb,
    const float* __restrict__ w_emb,
    float* __restrict__ out)
{
    __shared__ v2f kv[2][PT][PTS];      // [cc][row][col] {k,v}  (20.7 KB)

    const int bid0 = blockIdx.x;
    const int work = (bid0 & 7) * 512 + (bid0 >> 3);   // bijective XCD swizzle
    const int c0   = (work & 3) << 1;          // channel chunk {0,2,4,6}
    const int tile = (work >> 2) & 15;         // 4x4 tiles of 32x32
    const int bg   = work >> 6;                // b*8 + g
    const int g    = bg & 7;
    const int h0   = (tile >> 2) << 5;
    const int w0   = (tile & 3) << 5;
    const int tid  = threadIdx.x;
    const int ty   = tid >> 3;                 // 0..31
    const int x0   = (tid & 7) << 2;           // 0,4,..,28

    // ---- weights + emb -> SGPRs (readfirstlane-forced) ----
    float wk[2][8], wv[2][8], wq[2][8], eb[2][9];
    #pragma unroll
    for (int cc = 0; cc < 2; cc++) {
        const int c = c0 + cc;
        #pragma unroll
        for (int i = 0; i < 8; i++) {
            wk[cc][i] = sload(Wk[g * 64 + c * 8 + i]);
            wv[cc][i] = sload(Wv[g * 64 + c * 8 + i]);
            wq[cc][i] = sload(Wq[g * 64 + c * 8 + i]);
        }
        #pragma unroll
        for (int p = 0; p < 9; p++) {
            // channels 0-3: h_emb (ki = p/3); 4-7: w_emb (kj = p%3)
            eb[cc][p] = sload((c < 4) ? h_emb[(g * 4 + c) * 3 + p / 3]
                                      : w_emb[(g * 4 + c - 4) * 3 + p % 3]);
        }
    }

    const float* xb = x + (size_t)bg * 8 * HW;
    const int ibase = (h0 + ty) * WW + (w0 + x0);

    // ---- interior x: 4 px, 8 channels (dwordx4) ----
    v4f xi[8];
    #pragma unroll
    for (int i = 0; i < 8; i++)
        xi[i] = *reinterpret_cast<const v4f*>(xb + i * HW + ibase);

    // ---- conv (packed): k,v -> LDS, q -> regs ----
    v4f kk0 = 0.f, vv0 = 0.f, qq0 = 0.f, kk1 = 0.f, vv1 = 0.f, qq1 = 0.f;
    #pragma unroll
    for (int i = 0; i < 8; i++) {
        const v4f xv = xi[i];
        kk0 += wk[0][i] * xv;  vv0 += wv[0][i] * xv;  qq0 += wq[0][i] * xv;
        kk1 += wk[1][i] * xv;  vv1 += wv[1][i] * xv;  qq1 += wq[1][i] * xv;
    }
    #pragma unroll
    for (int px = 0; px < 4; px++) {
        kv[0][ty + 1][x0 + 1 + px] = (v2f){kk0[px], vv0[px]};
        kv[1][ty + 1][x0 + 1 + px] = (v2f){kk1[px], vv1[px]};
    }
    float q[2][4];
    #pragma unroll
    for (int px = 0; px < 4; px++) {
        q[0][px] = qq0[px] * LOG2E;
        q[1][px] = qq1[px] * LOG2E;
    }

    // ---- halo: 132 perimeter px on threads 0..131 (transient state) ----
    if (tid < 132) {
        int hpy, hpx;
        if (tid < 34)       { hpy = 0;        hpx = tid; }
        else if (tid < 68)  { hpy = 33;       hpx = tid - 34; }
        else if (tid < 100) { hpy = tid - 67; hpx = 0; }     // rows 1..32
        else                { hpy = tid - 99; hpx = 33; }
        const int gh = h0 + hpy - 1, gw = w0 + hpx - 1;
        const bool ok = (gh >= 0) & (gh < HH) & (gw >= 0) & (gw < WW);
        const int base = gh * WW + gw;
        float hk0 = 0.f, hv0 = 0.f, hk1 = 0.f, hv1 = 0.f;
        #pragma unroll
        for (int i = 0; i < 8; i++) {
            const float xv = ok ? xb[i * HW + base] : 0.0f;
            hk0 = fmaf(wk[0][i], xv, hk0);
            hv0 = fmaf(wv[0][i], xv, hv0);
            hk1 = fmaf(wk[1][i], xv, hk1);
            hv1 = fmaf(wv[1][i], xv, hv1);
        }
        kv[0][hpy][hpx] = (v2f){hk0, hv0};
        kv[1][hpy][hpx] = (v2f){hk1, hv1};
    }
    __syncthreads();

    // ---- attention: scalar streaming softmax (no vector rebuilds) ----
    float s[2][4] = {{0.f,0.f,0.f,0.f},{0.f,0.f,0.f,0.f}};
    float o[2][4] = {{0.f,0.f,0.f,0.f},{0.f,0.f,0.f,0.f}};
    #pragma unroll
    for (int dh = 0; dh < 3; dh++) {
        #pragma unroll
        for (int cc = 0; cc < 2; cc++) {
            const v2f* row = &kv[cc][ty + dh][x0];
            const v4f a  = *reinterpret_cast<const v4f*>(row);      // k0 v0 k1 v1
            const v4f bq = *reinterpret_cast<const v4f*>(row + 2);  // k2 v2 k3 v3
            const v4f cq = *reinterpret_cast<const v4f*>(row + 4);  // k4 v4 k5 v5
            const float kw[6] = {a.x, a.z, bq.x, bq.z, cq.x, cq.z};
            const float vw[6] = {a.y, a.w, bq.y, bq.w, cq.y, cq.w};
            #pragma unroll
            for (int px = 0; px < 4; px++) {
                const float ql = q[cc][px];
                #pragma unroll
                for (int dw = 0; dw < 3; dw++) {
                    const float e = __builtin_amdgcn_exp2f(
                        ql * (kw[px + dw] + eb[cc][dh * 3 + dw]));
                    s[cc][px] += e;
                    o[cc][px] = fmaf(e, vw[px + dw], o[cc][px]);
                }
            }
        }
    }

    // ---- normalize + store (dwordx4 per channel) ----
    v4f r0, r1;
    #pragma unroll
    for (int px = 0; px < 4; px++) {
        r0[px] = o[0][px] * __builtin_amdgcn_rcpf(s[0][px]);
        r1[px] = o[1][px] * __builtin_amdgcn_rcpf(s[1][px]);
    }
    *reinterpret_cast<v4f*>(out + (size_t)(bg * 8 + c0 + 0) * HW + ibase) = r0;
    *reinterpret_cast<v4f*>(out + (size_t)(bg * 8 + c0 + 1) * HW + ibase) = r1;
}

extern "C" void kernel_launch(void* const* d_in, const int* in_sizes, int n_in,
                              void* d_out, int out_size, void* d_ws, size_t ws_size,
                              hipStream_t stream) {
    const float* x    = (const float*)d_in[0];
    const float* Wq   = (const float*)d_in[1];
    const float* Wk   = (const float*)d_in[2];
    const float* Wv   = (const float*)d_in[3];
    const float* h_e  = (const float*)d_in[4];
    const float* w_e  = (const float*)d_in[5];
    float* out = (float*)d_out;

    dim3 grid(8 * 8 * 16 * 4);   // (b,g) x 4x4 tiles x 4 channel-chunks
    dim3 block(256);
    sab_fused<<<grid, block, 0, stream>>>(x, Wq, Wk, Wv, h_e, w_e, out);
}